// Round 9
// baseline (156.154 us; speedup 1.0000x reference)
//
#include <hip/hip_runtime.h>
#include <math.h>

#define NW     10
#define DIM    1024
#define QDEPTH 16

typedef __attribute__((ext_vector_type(8))) _Float16 f16x8;
typedef __attribute__((ext_vector_type(4))) _Float16 f16x4;
typedef __attribute__((ext_vector_type(2))) _Float16 f16x2;
typedef __attribute__((ext_vector_type(4))) float    f32x4;

// ---------------- ws layout ----------------
#define WS_GATES 0
#define WS_IPERM 8192
#define WS_INVS  81920
#define WS_XH    (1u << 20)
#define WS_BIL   (17u << 20)

// padded LDS slot (float2 units): breaks power-of-2 bank conflicts
#define SLOT(i) ((i) + ((i) >> 4))

__device__ inline void gate2(const float* __restrict__ g, float2& p0, float2& p1) {
    float m00r = g[0], m00i = g[1], m01r = g[2], m01i = g[3];
    float m10r = g[4], m10i = g[5], m11r = g[6], m11i = g[7];
    float n0x = m00r*p0.x - m00i*p0.y + m01r*p1.x - m01i*p1.y;
    float n0y = m00r*p0.y + m00i*p0.x + m01r*p1.y + m01i*p1.x;
    float n1x = m10r*p0.x - m10i*p0.y + m11r*p1.x - m11i*p1.y;
    float n1y = m10r*p0.y + m10i*p0.x + m11r*p1.y + m11i*p1.x;
    p0 = make_float2(n0x, n0y);
    p1 = make_float2(n1x, n1y);
}

__global__ __launch_bounds__(1024)
void prep_kernel(const float* __restrict__ w, float* __restrict__ gates,
                 int* __restrict__ iperm) {
    int t = threadIdx.x;
    const float PI = 3.14159265358979323846f;
    if (t < QDEPTH * NW) {
        float phi   = tanhf(w[t*3 + 0]) * PI;
        float theta = tanhf(w[t*3 + 1]) * PI;
        float omega = tanhf(w[t*3 + 2]) * PI;
        float ch = cosf(theta * 0.5f), sh = sinf(theta * 0.5f);
        float ap = (phi + omega) * 0.5f;
        float am = (phi - omega) * 0.5f;
        float* g = gates + t * 8;
        g[0] =  cosf(ap) * ch;  g[1] = -sinf(ap) * ch;   // m00
        g[2] = -cosf(am) * sh;  g[3] = -sinf(am) * sh;   // m01
        g[4] =  cosf(am) * sh;  g[5] = -sinf(am) * sh;   // m10
        g[6] =  cosf(ap) * ch;  g[7] =  sinf(ap) * ch;   // m11
    }
    int v = t;
    for (int l = 0; l < QDEPTH; ++l) {
        int r = (l % (NW - 1)) + 1;
        int u = v;
        for (int wq = NW - 1; wq >= 0; --wq) {
            int bc = 9 - wq;
            int bt = 9 - ((wq + r) % NW);
            u ^= ((u >> bc) & 1) << bt;
        }
        iperm[l * DIM + v] = u;
    }
}

// Wave-per-column register builder. Block v (64 threads = 1 wave) simulates
// basis state e_v with 16 amps/thread in registers. Bit split 4+4+2:
//   L_A: free bits[9:6]=r, fixed bits[5:0]=lane  -> pass A (wires 0..3) in-reg
//   L_B: free bits[5:2]=r, fixed bits[9:6]=l>>2, bits[1:0]=l&3 -> pass B (wires 4..7)
//   L_C: free bits[9:8]=r>>2, bits[1:0]=r&3, fixed bits[7:2]=l -> pass C (wires 8,9)
// Redistributions are wave-synchronous LDS round-trips (no barriers). CNOT perm
// fused into the layer-boundary gather; final perm fused into the output write.
__global__ __launch_bounds__(64)
void ubuild_kernel(const float* __restrict__ gates, const int* __restrict__ iperm,
                   _Float16* __restrict__ Ucol) {
    __shared__ float2 st[DIM + 64];
    const int v = blockIdx.x;
    const int l = threadIdx.x;     // lane 0..63

    // layer-invariant slot tables
    int aA[16], aB[16], aC[16];
    #pragma unroll
    for (int r = 0; r < 16; ++r) {
        const int iA = (r << 6) | l;
        const int iB = ((l >> 2) << 6) | (r << 2) | (l & 3);
        const int iC = ((r >> 2) << 8) | (l << 2) | (r & 3);
        aA[r] = SLOT(iA);
        aB[r] = SLOT(iB);
        aC[r] = SLOT(iC);
    }

    float re[16], im[16];
    #pragma unroll
    for (int r = 0; r < 16; ++r) {
        re[r] = (((r << 6) | l) == v) ? 1.0f : 0.0f;
        im[r] = 0.0f;
    }

    for (int ly = 0; ly < QDEPTH; ++ly) {
        const float* gl = gates + ly * (NW * 8);
        // prefetch this layer's perm indices (used at the bottom; coalesced)
        const int* ipl = iperm + ly * DIM;
        int pidx[16];
        #pragma unroll
        for (int r = 0; r < 16; ++r) pidx[r] = ipl[(r << 6) | l];

        // ---- pass A: bits 9..6 (r-bits 3..0), wires 0..3 ----
        #pragma unroll
        for (int k = 0; k < 4; ++k) {              // k=0 -> bit9/wire0
            const float* g = gl + k * 8;
            const int m = 8 >> k;                  // r-bit mask 8,4,2,1
            #pragma unroll
            for (int r = 0; r < 16; ++r)
                if (!(r & m)) {
                    float2 p0 = make_float2(re[r], im[r]);
                    float2 p1 = make_float2(re[r | m], im[r | m]);
                    gate2(g, p0, p1);
                    re[r] = p0.x;     im[r] = p0.y;
                    re[r | m] = p1.x; im[r | m] = p1.y;
                }
        }

        // ---- RT1: L_A -> L_B ----
        #pragma unroll
        for (int r = 0; r < 16; ++r) st[aA[r]] = make_float2(re[r], im[r]);
        asm volatile("s_waitcnt lgkmcnt(0)" ::: "memory");
        #pragma unroll
        for (int r = 0; r < 16; ++r) { float2 a = st[aB[r]]; re[r] = a.x; im[r] = a.y; }

        // ---- pass B: bits 5..2 (r-bits 3..0), wires 4..7 ----
        #pragma unroll
        for (int k = 0; k < 4; ++k) {              // k=0 -> bit5/wire4
            const float* g = gl + (4 + k) * 8;
            const int m = 8 >> k;
            #pragma unroll
            for (int r = 0; r < 16; ++r)
                if (!(r & m)) {
                    float2 p0 = make_float2(re[r], im[r]);
                    float2 p1 = make_float2(re[r | m], im[r | m]);
                    gate2(g, p0, p1);
                    re[r] = p0.x;     im[r] = p0.y;
                    re[r | m] = p1.x; im[r | m] = p1.y;
                }
        }

        // ---- RT2: L_B -> L_C ----  (aB slots uniquely owned: same-thread dep)
        #pragma unroll
        for (int r = 0; r < 16; ++r) st[aB[r]] = make_float2(re[r], im[r]);
        asm volatile("s_waitcnt lgkmcnt(0)" ::: "memory");
        #pragma unroll
        for (int r = 0; r < 16; ++r) { float2 a = st[aC[r]]; re[r] = a.x; im[r] = a.y; }

        // ---- pass C: bits 1,0 (r-bits 1,0), wires 8,9 ----
        #pragma unroll
        for (int k = 0; k < 2; ++k) {              // k=0 -> bit1/wire8
            const float* g = gl + (8 + k) * 8;
            const int m = 2 >> k;                  // 2,1
            #pragma unroll
            for (int r = 0; r < 16; ++r)
                if (!(r & m)) {
                    float2 p0 = make_float2(re[r], im[r]);
                    float2 p1 = make_float2(re[r | m], im[r | m]);
                    gate2(g, p0, p1);
                    re[r] = p0.x;     im[r] = p0.y;
                    re[r | m] = p1.x; im[r | m] = p1.y;
                }
        }

        // ---- RT3: write L_C, then perm-fused gather ----
        #pragma unroll
        for (int r = 0; r < 16; ++r) st[aC[r]] = make_float2(re[r], im[r]);
        asm volatile("s_waitcnt lgkmcnt(0)" ::: "memory");

        if (ly < QDEPTH - 1) {
            // next-layer L_A with fused perm: amp'[iA] = st[SLOT(G_ly(iA))]
            #pragma unroll
            for (int r = 0; r < 16; ++r) {
                float2 a = st[SLOT(pidx[r])];
                re[r] = a.x; im[r] = a.y;
            }
            // ensure all gathers complete before next layer's RT1 overwrites st
            asm volatile("s_waitcnt lgkmcnt(0)" ::: "memory");
        } else {
            // output with fused final perm: col[i] for i = (r<<6)|l
            _Float16* col = Ucol + (size_t)v * 2048;
            #pragma unroll
            for (int r = 0; r < 16; ++r) {
                float2 a = st[SLOT(pidx[r])];
                f16x2 p;
                p[0] = (_Float16)a.x;
                p[1] = (_Float16)a.y;
                *(f16x2*)(col + 2 * (((r << 6) | l))) = p;
            }
        }
    }
}

// Bil[n][k] = Ucol[k][n], n<2048, k<1024. LDS-tiled 64x64 transpose.
__global__ __launch_bounds__(256)
void transpose_kernel(const _Float16* __restrict__ Ucol, _Float16* __restrict__ Bil) {
    __shared__ _Float16 tile[64][72];
    const int bx = blockIdx.x;          // n-tile: 0..31
    const int by = blockIdx.y;          // k-tile: 0..15
    const int t  = threadIdx.x;
    const int r  = t >> 3;              // 0..31
    const int c8 = (t & 7) * 8;         // 0..56

    #pragma unroll
    for (int kk = 0; kk < 64; kk += 32) {
        *(f16x8*)&tile[kk + r][c8] =
            *(const f16x8*)(Ucol + (size_t)(by * 64 + kk + r) * 2048 + bx * 64 + c8);
    }
    __syncthreads();
    #pragma unroll
    for (int nn = 0; nn < 64; nn += 32) {
        f16x8 o;
        #pragma unroll
        for (int j = 0; j < 8; ++j) o[j] = tile[c8 + j][nn + r];
        *(f16x8*)(Bil + (size_t)(bx * 64 + nn + r) * 1024 + by * 64 + c8) = o;
    }
}

// Per-row sumsq + f16 cast. One wave per batch row.
__global__ __launch_bounds__(64)
void normcast_kernel(const float* __restrict__ x, _Float16* __restrict__ Xh,
                     float* __restrict__ invs) {
    const int b = blockIdx.x;
    const int l = threadIdx.x;
    const float4* xr = (const float4*)(x + (size_t)b * DIM);
    float4 v[4];
    float ss = 0.f;
    #pragma unroll
    for (int c = 0; c < 4; ++c) {
        v[c] = xr[l + c * 64];
        ss += v[c].x*v[c].x + v[c].y*v[c].y + v[c].z*v[c].z + v[c].w*v[c].w;
    }
    #pragma unroll
    for (int o = 32; o >= 1; o >>= 1) ss += __shfl_down(ss, o, 64);
    ss = __shfl(ss, 0, 64);
    if (l == 0) invs[b] = 1024.0f / ss;
    f16x4* xo = (f16x4*)(Xh + (size_t)b * DIM);
    #pragma unroll
    for (int c = 0; c < 4; ++c) {
        f16x4 h;
        h[0] = (_Float16)v[c].x; h[1] = (_Float16)v[c].y;
        h[2] = (_Float16)v[c].z; h[3] = (_Float16)v[c].w;
        xo[l + c * 64] = h;
    }
}

// ---------------- GEMM: 256x256 tile, BK=64, 8-phase-style schedule ----------
// (unchanged from round 7 - verified)
#define GBK 64
#define NKT 16     // 1024 / 64

__device__ __forceinline__ f16x8 ldsfrag(const _Float16* base, int hrow, int c) {
    return *(const f16x8*)(base + hrow * 64 + ((c ^ (hrow & 7)) << 3));
}

__global__ __launch_bounds__(512, 2)
void gemm_kernel(const _Float16* __restrict__ A, const _Float16* __restrict__ B,
                 const float* __restrict__ invs, float* __restrict__ out) {
    __shared__ _Float16 As[2][2][8192];   // [buf][M-half][128 rows x 64 k], 64 KB
    __shared__ _Float16 Bs[2][2][8192];   // [buf][N-half][...], 64 KB
    const int t    = threadIdx.x;
    const int lane = t & 63;
    const int wid  = t >> 6;      // 0..7
    const int wm   = wid >> 2;    // 0..1 : M-half (128 rows)
    const int wn   = wid & 3;     // 0..3 : N-quarter (64 cols)

    // T1: XCD x gets m-panels 4x..4x+3, all 8 n-panels
    const int bid   = blockIdx.x;          // 256 blocks
    const int local = bid >> 3;            // 0..31
    const int m0 = ((bid & 7) * 4 + (local & 3)) * 256;
    const int n0 = (local >> 2) * 256;

    const _Float16* Ag0 = A + (size_t)m0 * 1024;          // A-half0 (rows m0..+127)
    const _Float16* Ag1 = A + (size_t)(m0 + 128) * 1024;  // A-half1
    const _Float16* Bg0 = B + (size_t)n0 * 1024;
    const _Float16* Bg1 = B + (size_t)(n0 + 128) * 1024;

    const int srow = t >> 3;                       // 0..63 (and +64)
    const int sgc  = ((t & 7) ^ (srow & 7)) * 8;   // swizzled source chunk, elems
    #define STAGE_HALF(dst, gbase, kt)                                              \
        do {                                                                        \
            __builtin_amdgcn_global_load_lds(                                       \
                (const __attribute__((address_space(1))) void*)                     \
                    ((gbase) + (size_t)srow * 1024 + (kt) * 64 + sgc),              \
                (__attribute__((address_space(3))) void*)((dst) + t * 8), 16, 0, 0);\
            __builtin_amdgcn_global_load_lds(                                       \
                (const __attribute__((address_space(1))) void*)                     \
                    ((gbase) + (size_t)(64 + srow) * 1024 + (kt) * 64 + sgc),       \
                (__attribute__((address_space(3))) void*)((dst) + 4096 + t * 8),    \
                16, 0, 0);                                                          \
        } while (0)

    f32x4 acc[8][4];
    const f32x4 zero = {0.f, 0.f, 0.f, 0.f};
    #pragma unroll
    for (int i = 0; i < 8; ++i)
        #pragma unroll
        for (int j = 0; j < 4; ++j) acc[i][j] = zero;

    const int fr = lane & 15;       // frag row within 16
    const int ch = lane >> 4;       // 16B chunk within 32-k sub-tile

    // ---- prologue: tile 0 fully + A-half0 of tile 1; wait tile 0 only ----
    STAGE_HALF(&As[0][0][0], Ag0, 0);
    STAGE_HALF(&As[0][1][0], Ag1, 0);
    STAGE_HALF(&Bs[0][0][0], Bg0, 0);
    STAGE_HALF(&Bs[0][1][0], Bg1, 0);
    STAGE_HALF(&As[1][0][0], Ag0, 1);
    asm volatile("s_waitcnt vmcnt(2)" ::: "memory");
    __builtin_amdgcn_s_barrier();
    __builtin_amdgcn_sched_barrier(0);

    for (int tk = 0; tk < NKT; ++tk) {
        const int buf = tk & 1, nbuf = buf ^ 1;
        const _Float16* Ab = &As[buf][wm][0];
        const _Float16* Bb = &Bs[buf][wn >> 1][0];
        const int bro = (wn & 1) * 64;            // B hrow offset within half

        f16x8 afl[4][2], afh[4][2], bfa[2][2], bfb[2][2];

        // ---- phase 0: read afl + bfa; stage A-half1(t+1) ----
        #pragma unroll
        for (int m = 0; m < 4; ++m)
            #pragma unroll
            for (int ks = 0; ks < 2; ++ks)
                afl[m][ks] = ldsfrag(Ab, m * 16 + fr, ks * 4 + ch);
        #pragma unroll
        for (int n = 0; n < 2; ++n)
            #pragma unroll
            for (int ks = 0; ks < 2; ++ks)
                bfa[n][ks] = ldsfrag(Bb, bro + n * 16 + fr, ks * 4 + ch);
        if (tk + 1 < NKT) STAGE_HALF(&As[nbuf][1][0], Ag1, tk + 1);
        __builtin_amdgcn_s_barrier();
        asm volatile("s_waitcnt lgkmcnt(0)" ::: "memory");
        __builtin_amdgcn_sched_barrier(0);
        __builtin_amdgcn_s_setprio(1);
        #pragma unroll
        for (int m = 0; m < 4; ++m)
            #pragma unroll
            for (int n = 0; n < 2; ++n)
                #pragma unroll
                for (int ks = 0; ks < 2; ++ks)
                    acc[m][n] = __builtin_amdgcn_mfma_f32_16x16x32_f16(
                        afl[m][ks], bfa[n][ks], acc[m][n], 0, 0, 0);
        __builtin_amdgcn_s_setprio(0);
        __builtin_amdgcn_s_barrier();
        __builtin_amdgcn_sched_barrier(0);

        // ---- phase 1: read bfb; stage B-half0(t+1) ----
        #pragma unroll
        for (int n = 0; n < 2; ++n)
            #pragma unroll
            for (int ks = 0; ks < 2; ++ks)
                bfb[n][ks] = ldsfrag(Bb, bro + (2 + n) * 16 + fr, ks * 4 + ch);
        if (tk + 1 < NKT) STAGE_HALF(&Bs[nbuf][0][0], Bg0, tk + 1);
        __builtin_amdgcn_s_barrier();
        asm volatile("s_waitcnt lgkmcnt(0)" ::: "memory");
        __builtin_amdgcn_sched_barrier(0);
        __builtin_amdgcn_s_setprio(1);
        #pragma unroll
        for (int m = 0; m < 4; ++m)
            #pragma unroll
            for (int n = 0; n < 2; ++n)
                #pragma unroll
                for (int ks = 0; ks < 2; ++ks)
                    acc[m][2 + n] = __builtin_amdgcn_mfma_f32_16x16x32_f16(
                        afl[m][ks], bfb[n][ks], acc[m][2 + n], 0, 0, 0);
        __builtin_amdgcn_s_setprio(0);
        __builtin_amdgcn_s_barrier();
        __builtin_amdgcn_sched_barrier(0);

        // ---- phase 2: read afh; stage B-half1(t+1) ----
        #pragma unroll
        for (int m = 0; m < 4; ++m)
            #pragma unroll
            for (int ks = 0; ks < 2; ++ks)
                afh[m][ks] = ldsfrag(Ab, 64 + m * 16 + fr, ks * 4 + ch);
        if (tk + 1 < NKT) STAGE_HALF(&Bs[nbuf][1][0], Bg1, tk + 1);
        __builtin_amdgcn_s_barrier();
        asm volatile("s_waitcnt lgkmcnt(0)" ::: "memory");
        __builtin_amdgcn_sched_barrier(0);
        __builtin_amdgcn_s_setprio(1);
        #pragma unroll
        for (int m = 0; m < 4; ++m)
            #pragma unroll
            for (int n = 0; n < 2; ++n)
                #pragma unroll
                for (int ks = 0; ks < 2; ++ks)
                    acc[4 + m][n] = __builtin_amdgcn_mfma_f32_16x16x32_f16(
                        afh[m][ks], bfa[n][ks], acc[4 + m][n], 0, 0, 0);
        __builtin_amdgcn_s_setprio(0);
        __builtin_amdgcn_s_barrier();
        __builtin_amdgcn_sched_barrier(0);

        // ---- phase 3: stage A-half0(t+2) into As[buf][0] (dead since p2) ----
        if (tk + 2 < NKT) STAGE_HALF(&As[buf][0][0], Ag0, tk + 2);
        __builtin_amdgcn_s_barrier();
        asm volatile("s_waitcnt lgkmcnt(0)" ::: "memory");
        __builtin_amdgcn_sched_barrier(0);
        __builtin_amdgcn_s_setprio(1);
        #pragma unroll
        for (int m = 0; m < 4; ++m)
            #pragma unroll
            for (int n = 0; n < 2; ++n)
                #pragma unroll
                for (int ks = 0; ks < 2; ++ks)
                    acc[4 + m][2 + n] = __builtin_amdgcn_mfma_f32_16x16x32_f16(
                        afh[m][ks], bfb[n][ks], acc[4 + m][2 + n], 0, 0, 0);
        __builtin_amdgcn_s_setprio(0);
        // boundary: tile t+1 ready when only A0(t+2)'s 2 loads remain in flight
        if (tk + 1 < NKT) {
            if (tk + 2 < NKT) asm volatile("s_waitcnt vmcnt(2)" ::: "memory");
            else              asm volatile("s_waitcnt vmcnt(0)" ::: "memory");
            __builtin_amdgcn_s_barrier();
            __builtin_amdgcn_sched_barrier(0);
        }
    }
    #undef STAGE_HALF

    // epilogue: C row = m0+wm*128+mf*16+(lane>>4)*4+r ; col = n0+wn*64+nf*16+(lane&15)
    const int colf = lane & 15;
    const int rowf = (lane >> 4) * 4;
    #pragma unroll
    for (int mf = 0; mf < 8; ++mf) {
        #pragma unroll
        for (int nf = 0; nf < 4; ++nf) {
            const int n = n0 + wn * 64 + nf * 16 + colf;
            #pragma unroll
            for (int r = 0; r < 4; ++r) {
                const int row = m0 + wm * 128 + mf * 16 + rowf + r;
                float vv = acc[mf][nf][r];
                float sq = vv * vv;
                float other = __shfl_xor(sq, 1, 64);
                if (!(lane & 1)) {
                    float p = fminf((sq + other) * invs[row], 1.0f);
                    out[(size_t)row * DIM + (n >> 1)] = p;
                }
            }
        }
    }
}

extern "C" void kernel_launch(void* const* d_in, const int* in_sizes, int n_in,
                              void* d_out, int out_size, void* d_ws, size_t ws_size,
                              hipStream_t stream) {
    const float* x = (const float*)d_in[0];     // (8192,1,32,32) fp32
    const float* w = (const float*)d_in[1];     // (16,10,3) fp32
    float* out = (float*)d_out;                 // (8192,1,32,32) fp32

    char* ws = (char*)d_ws;
    float*     gates = (float*)(ws + WS_GATES);
    int*       iperm = (int*)(ws + WS_IPERM);
    float*     invs  = (float*)(ws + WS_INVS);
    _Float16*  Xh    = (_Float16*)(ws + WS_XH);
    _Float16*  Bil   = (_Float16*)(ws + WS_BIL);
    // Ucol scratch lives in d_out (4 MB of its 32 MB); consumed by transpose
    // before gemm overwrites every element of d_out.
    _Float16*  Ucol  = (_Float16*)d_out;

    prep_kernel<<<1, 1024, 0, stream>>>(w, gates, iperm);
    normcast_kernel<<<8192, 64, 0, stream>>>(x, Xh, invs);
    ubuild_kernel<<<1024, 64, 0, stream>>>(gates, iperm, Ucol);
    transpose_kernel<<<dim3(32, 16), 256, 0, stream>>>(Ucol, Bil);
    gemm_kernel<<<256, 512, 0, stream>>>(Xh, Bil, invs, out);
}

// Round 10
// 146.085 us; speedup vs baseline: 1.0689x; 1.0689x over previous
//
#include <hip/hip_runtime.h>
#include <math.h>

#define NW     10
#define DIM    1024
#define QDEPTH 16

typedef __attribute__((ext_vector_type(8))) _Float16 f16x8;
typedef __attribute__((ext_vector_type(4))) _Float16 f16x4;
typedef __attribute__((ext_vector_type(2))) _Float16 f16x2;
typedef __attribute__((ext_vector_type(4))) float    f32x4;

// ---------------- ws layout ----------------
#define WS_GATES 0
#define WS_IPERM 8192
#define WS_INVS  81920
#define WS_XH    (1u << 20)
#define WS_BIL   (17u << 20)

// padded LDS slot: breaks power-of-2 stride bank conflicts
#define SLOT(i) ((i) + ((i) >> 4))

__device__ inline void gate2(const float* __restrict__ g, float2& p0, float2& p1) {
    float m00r = g[0], m00i = g[1], m01r = g[2], m01i = g[3];
    float m10r = g[4], m10i = g[5], m11r = g[6], m11i = g[7];
    float n0x = m00r*p0.x - m00i*p0.y + m01r*p1.x - m01i*p1.y;
    float n0y = m00r*p0.y + m00i*p0.x + m01r*p1.y + m01i*p1.x;
    float n1x = m10r*p0.x - m10i*p0.y + m11r*p1.x - m11i*p1.y;
    float n1y = m10r*p0.y + m10i*p0.x + m11r*p1.y + m11i*p1.x;
    p0 = make_float2(n0x, n0y);
    p1 = make_float2(n1x, n1y);
}

__global__ __launch_bounds__(1024)
void prep_kernel(const float* __restrict__ w, float* __restrict__ gates,
                 int* __restrict__ iperm) {
    int t = threadIdx.x;
    const float PI = 3.14159265358979323846f;
    if (t < QDEPTH * NW) {
        // Rot(phi,theta,omega) = RZ(omega) RY(theta) RZ(phi); angles = tanh(w)*pi
        float phi   = tanhf(w[t*3 + 0]) * PI;
        float theta = tanhf(w[t*3 + 1]) * PI;
        float omega = tanhf(w[t*3 + 2]) * PI;
        float ch = cosf(theta * 0.5f), sh = sinf(theta * 0.5f);
        float ap = (phi + omega) * 0.5f;
        float am = (phi - omega) * 0.5f;
        float* g = gates + t * 8;
        g[0] =  cosf(ap) * ch;  g[1] = -sinf(ap) * ch;   // m00
        g[2] = -cosf(am) * sh;  g[3] = -sinf(am) * sh;   // m01
        g[4] =  cosf(am) * sh;  g[5] = -sinf(am) * sh;   // m10
        g[6] =  cosf(ap) * ch;  g[7] =  sinf(ap) * ch;   // m11
    }
    // Forward CNOT-block gather (round-1 verified): state'[v] = state[G_l(v)]
    int v = t;
    for (int l = 0; l < QDEPTH; ++l) {
        int r = (l % (NW - 1)) + 1;
        int u = v;
        for (int wq = NW - 1; wq >= 0; --wq) {
            int bc = 9 - wq;
            int bt = 9 - ((wq + r) % NW);
            u ^= ((u >> bc) & 1) << bt;
        }
        iperm[l * DIM + v] = u;
    }
}

// Dual-column builder (round-8 structure, 2 columns per block for ILP-2).
// Block handles basis states v0=2*bid, v1=v0+1; per-layer overheads (gate
// loads, iperm loads, barriers, index math) amortized over both columns.
// Perm P_{l-1} fused into the b=8 pass read; P_15 fused into output write.
__global__ __launch_bounds__(256)
void ubuild_kernel(const float* __restrict__ gates, const int* __restrict__ iperm,
                   _Float16* __restrict__ Ucol) {
    __shared__ float2 st0[DIM + 64];
    __shared__ float2 st1[DIM + 64];
    const int v0 = blockIdx.x * 2;
    const int v1 = v0 + 1;
    const int t  = threadIdx.x;

    // hoisted layer-invariant slot indices
    int s4[4];
    #pragma unroll
    for (int k = 0; k < 4; ++k) s4[k] = SLOT(t + k * 256);
    int sq[4][4];
    #pragma unroll
    for (int pp = 0; pp < 4; ++pp) {
        const int b = 2 * pp;
        const int low = t & ((1 << b) - 1);
        const int i00 = ((t >> b) << (b + 2)) | low;
        sq[pp][0] = SLOT(i00);
        sq[pp][1] = SLOT(i00 | (1 << b));
        sq[pp][2] = SLOT(i00 | (2 << b));
        sq[pp][3] = SLOT(i00 | (3 << b));
    }

    #pragma unroll
    for (int k = 0; k < 4; ++k) {
        int i = t + k * 256;
        st0[s4[k]] = make_float2(i == v0 ? 1.f : 0.f, 0.f);
        st1[s4[k]] = make_float2(i == v1 ? 1.f : 0.f, 0.f);
    }
    __syncthreads();

    for (int l = 0; l < QDEPTH; ++l) {
        const float* gl = gates + l * NW * 8;

        // ---- pass b=8 (wires 0,1) with fused gather of perm l-1 ----
        float2 p00, p01, p10, p11, q00, q01, q10, q11;
        if (l == 0) {
            p00 = st0[s4[0]]; p01 = st0[s4[1]]; p10 = st0[s4[2]]; p11 = st0[s4[3]];
            q00 = st1[s4[0]]; q01 = st1[s4[1]]; q10 = st1[s4[2]]; q11 = st1[s4[3]];
        } else {
            const int* ipm = iperm + (l - 1) * DIM;
            int g0 = ipm[t], g1 = ipm[t + 256], g2 = ipm[t + 512], g3 = ipm[t + 768];
            const int h0 = SLOT(g0), h1 = SLOT(g1), h2 = SLOT(g2), h3 = SLOT(g3);
            p00 = st0[h0]; p01 = st0[h1]; p10 = st0[h2]; p11 = st0[h3];
            q00 = st1[h0]; q01 = st1[h1]; q10 = st1[h2]; q11 = st1[h3];
        }
        gate2(gl + 0, p00, p10);   // wire 0 (bit 9)
        gate2(gl + 0, p01, p11);
        gate2(gl + 8, p00, p01);   // wire 1 (bit 8)
        gate2(gl + 8, p10, p11);
        gate2(gl + 0, q00, q10);
        gate2(gl + 0, q01, q11);
        gate2(gl + 8, q00, q01);
        gate2(gl + 8, q10, q11);
        if (l) __syncthreads();    // drain gathers before canonical writes
        st0[s4[0]] = p00; st0[s4[1]] = p01; st0[s4[2]] = p10; st0[s4[3]] = p11;
        st1[s4[0]] = q00; st1[s4[1]] = q01; st1[s4[2]] = q10; st1[s4[3]] = q11;
        __syncthreads();

        // ---- passes b = 6,4,2,0: thread-exclusive quads, both columns ----
        #pragma unroll
        for (int pp = 3; pp >= 0; --pp) {
            const int b = 2 * pp;
            const float* gh = gl + (8 - b) * 8;   // gate on bit b+1 (wire 8-b)
            const float* gm = gl + (9 - b) * 8;   // gate on bit b   (wire 9-b)
            float2 c00 = st0[sq[pp][0]], c01 = st0[sq[pp][1]];
            float2 c10 = st0[sq[pp][2]], c11 = st0[sq[pp][3]];
            float2 d00 = st1[sq[pp][0]], d01 = st1[sq[pp][1]];
            float2 d10 = st1[sq[pp][2]], d11 = st1[sq[pp][3]];
            gate2(gh, c00, c10);
            gate2(gh, c01, c11);
            gate2(gm, c00, c01);
            gate2(gm, c10, c11);
            gate2(gh, d00, d10);
            gate2(gh, d01, d11);
            gate2(gm, d00, d01);
            gate2(gm, d10, d11);
            st0[sq[pp][0]] = c00; st0[sq[pp][1]] = c01;
            st0[sq[pp][2]] = c10; st0[sq[pp][3]] = c11;
            st1[sq[pp][0]] = d00; st1[sq[pp][1]] = d01;
            st1[sq[pp][2]] = d10; st1[sq[pp][3]] = d11;
            __syncthreads();
        }
    }

    // ---- output with fused final perm ----
    const int* ipl = iperm + (QDEPTH - 1) * DIM;
    _Float16* col0 = Ucol + (size_t)v0 * 2048;
    _Float16* col1 = Ucol + (size_t)v1 * 2048;
    #pragma unroll
    for (int k = 0; k < 4; ++k) {
        int i = t + k * 256;
        int h = SLOT(ipl[i]);
        float2 a = st0[h];
        float2 b = st1[h];
        f16x2 pa, pb;
        pa[0] = (_Float16)a.x; pa[1] = (_Float16)a.y;
        pb[0] = (_Float16)b.x; pb[1] = (_Float16)b.y;
        *(f16x2*)(col0 + 2 * i) = pa;
        *(f16x2*)(col1 + 2 * i) = pb;
    }
}

// Bil[n][k] = Ucol[k][n], n<2048, k<1024. LDS-tiled 64x64 transpose.
__global__ __launch_bounds__(256)
void transpose_kernel(const _Float16* __restrict__ Ucol, _Float16* __restrict__ Bil) {
    __shared__ _Float16 tile[64][72];
    const int bx = blockIdx.x;          // n-tile: 0..31
    const int by = blockIdx.y;          // k-tile: 0..15
    const int t  = threadIdx.x;
    const int r  = t >> 3;              // 0..31
    const int c8 = (t & 7) * 8;         // 0..56

    #pragma unroll
    for (int kk = 0; kk < 64; kk += 32) {
        *(f16x8*)&tile[kk + r][c8] =
            *(const f16x8*)(Ucol + (size_t)(by * 64 + kk + r) * 2048 + bx * 64 + c8);
    }
    __syncthreads();
    #pragma unroll
    for (int nn = 0; nn < 64; nn += 32) {
        f16x8 o;
        #pragma unroll
        for (int j = 0; j < 8; ++j) o[j] = tile[c8 + j][nn + r];
        *(f16x8*)(Bil + (size_t)(bx * 64 + nn + r) * 1024 + by * 64 + c8) = o;
    }
}

// Per-row sumsq + f16 cast. One wave per batch row.
__global__ __launch_bounds__(64)
void normcast_kernel(const float* __restrict__ x, _Float16* __restrict__ Xh,
                     float* __restrict__ invs) {
    const int b = blockIdx.x;
    const int l = threadIdx.x;
    const float4* xr = (const float4*)(x + (size_t)b * DIM);
    float4 v[4];
    float ss = 0.f;
    #pragma unroll
    for (int c = 0; c < 4; ++c) {
        v[c] = xr[l + c * 64];
        ss += v[c].x*v[c].x + v[c].y*v[c].y + v[c].z*v[c].z + v[c].w*v[c].w;
    }
    #pragma unroll
    for (int o = 32; o >= 1; o >>= 1) ss += __shfl_down(ss, o, 64);
    ss = __shfl(ss, 0, 64);
    if (l == 0) invs[b] = 1024.0f / ss;
    f16x4* xo = (f16x4*)(Xh + (size_t)b * DIM);
    #pragma unroll
    for (int c = 0; c < 4; ++c) {
        f16x4 h;
        h[0] = (_Float16)v[c].x; h[1] = (_Float16)v[c].y;
        h[2] = (_Float16)v[c].z; h[3] = (_Float16)v[c].w;
        xo[l + c * 64] = h;
    }
}

// ---------------- GEMM: 256x256 tile, BK=64, 8-phase-style schedule ----------
// (unchanged from round 7 - verified)
#define GBK 64
#define NKT 16     // 1024 / 64

__device__ __forceinline__ f16x8 ldsfrag(const _Float16* base, int hrow, int c) {
    return *(const f16x8*)(base + hrow * 64 + ((c ^ (hrow & 7)) << 3));
}

__global__ __launch_bounds__(512, 2)
void gemm_kernel(const _Float16* __restrict__ A, const _Float16* __restrict__ B,
                 const float* __restrict__ invs, float* __restrict__ out) {
    __shared__ _Float16 As[2][2][8192];   // [buf][M-half][128 rows x 64 k], 64 KB
    __shared__ _Float16 Bs[2][2][8192];   // [buf][N-half][...], 64 KB
    const int t    = threadIdx.x;
    const int lane = t & 63;
    const int wid  = t >> 6;      // 0..7
    const int wm   = wid >> 2;    // 0..1 : M-half (128 rows)
    const int wn   = wid & 3;     // 0..3 : N-quarter (64 cols)

    // T1: XCD x gets m-panels 4x..4x+3, all 8 n-panels
    const int bid   = blockIdx.x;          // 256 blocks
    const int local = bid >> 3;            // 0..31
    const int m0 = ((bid & 7) * 4 + (local & 3)) * 256;
    const int n0 = (local >> 2) * 256;

    const _Float16* Ag0 = A + (size_t)m0 * 1024;          // A-half0 (rows m0..+127)
    const _Float16* Ag1 = A + (size_t)(m0 + 128) * 1024;  // A-half1
    const _Float16* Bg0 = B + (size_t)n0 * 1024;
    const _Float16* Bg1 = B + (size_t)(n0 + 128) * 1024;

    const int srow = t >> 3;                       // 0..63 (and +64)
    const int sgc  = ((t & 7) ^ (srow & 7)) * 8;   // swizzled source chunk, elems
    #define STAGE_HALF(dst, gbase, kt)                                              \
        do {                                                                        \
            __builtin_amdgcn_global_load_lds(                                       \
                (const __attribute__((address_space(1))) void*)                     \
                    ((gbase) + (size_t)srow * 1024 + (kt) * 64 + sgc),              \
                (__attribute__((address_space(3))) void*)((dst) + t * 8), 16, 0, 0);\
            __builtin_amdgcn_global_load_lds(                                       \
                (const __attribute__((address_space(1))) void*)                     \
                    ((gbase) + (size_t)(64 + srow) * 1024 + (kt) * 64 + sgc),       \
                (__attribute__((address_space(3))) void*)((dst) + 4096 + t * 8),    \
                16, 0, 0);                                                          \
        } while (0)

    f32x4 acc[8][4];
    const f32x4 zero = {0.f, 0.f, 0.f, 0.f};
    #pragma unroll
    for (int i = 0; i < 8; ++i)
        #pragma unroll
        for (int j = 0; j < 4; ++j) acc[i][j] = zero;

    const int fr = lane & 15;       // frag row within 16
    const int ch = lane >> 4;       // 16B chunk within 32-k sub-tile

    // ---- prologue: tile 0 fully + A-half0 of tile 1; wait tile 0 only ----
    STAGE_HALF(&As[0][0][0], Ag0, 0);
    STAGE_HALF(&As[0][1][0], Ag1, 0);
    STAGE_HALF(&Bs[0][0][0], Bg0, 0);
    STAGE_HALF(&Bs[0][1][0], Bg1, 0);
    STAGE_HALF(&As[1][0][0], Ag0, 1);
    asm volatile("s_waitcnt vmcnt(2)" ::: "memory");
    __builtin_amdgcn_s_barrier();
    __builtin_amdgcn_sched_barrier(0);

    for (int tk = 0; tk < NKT; ++tk) {
        const int buf = tk & 1, nbuf = buf ^ 1;
        const _Float16* Ab = &As[buf][wm][0];
        const _Float16* Bb = &Bs[buf][wn >> 1][0];
        const int bro = (wn & 1) * 64;            // B hrow offset within half

        f16x8 afl[4][2], afh[4][2], bfa[2][2], bfb[2][2];

        // ---- phase 0: read afl + bfa; stage A-half1(t+1) ----
        #pragma unroll
        for (int m = 0; m < 4; ++m)
            #pragma unroll
            for (int ks = 0; ks < 2; ++ks)
                afl[m][ks] = ldsfrag(Ab, m * 16 + fr, ks * 4 + ch);
        #pragma unroll
        for (int n = 0; n < 2; ++n)
            #pragma unroll
            for (int ks = 0; ks < 2; ++ks)
                bfa[n][ks] = ldsfrag(Bb, bro + n * 16 + fr, ks * 4 + ch);
        if (tk + 1 < NKT) STAGE_HALF(&As[nbuf][1][0], Ag1, tk + 1);
        __builtin_amdgcn_s_barrier();
        asm volatile("s_waitcnt lgkmcnt(0)" ::: "memory");
        __builtin_amdgcn_sched_barrier(0);
        __builtin_amdgcn_s_setprio(1);
        #pragma unroll
        for (int m = 0; m < 4; ++m)
            #pragma unroll
            for (int n = 0; n < 2; ++n)
                #pragma unroll
                for (int ks = 0; ks < 2; ++ks)
                    acc[m][n] = __builtin_amdgcn_mfma_f32_16x16x32_f16(
                        afl[m][ks], bfa[n][ks], acc[m][n], 0, 0, 0);
        __builtin_amdgcn_s_setprio(0);
        __builtin_amdgcn_s_barrier();
        __builtin_amdgcn_sched_barrier(0);

        // ---- phase 1: read bfb; stage B-half0(t+1) ----
        #pragma unroll
        for (int n = 0; n < 2; ++n)
            #pragma unroll
            for (int ks = 0; ks < 2; ++ks)
                bfb[n][ks] = ldsfrag(Bb, bro + (2 + n) * 16 + fr, ks * 4 + ch);
        if (tk + 1 < NKT) STAGE_HALF(&Bs[nbuf][0][0], Bg0, tk + 1);
        __builtin_amdgcn_s_barrier();
        asm volatile("s_waitcnt lgkmcnt(0)" ::: "memory");
        __builtin_amdgcn_sched_barrier(0);
        __builtin_amdgcn_s_setprio(1);
        #pragma unroll
        for (int m = 0; m < 4; ++m)
            #pragma unroll
            for (int n = 0; n < 2; ++n)
                #pragma unroll
                for (int ks = 0; ks < 2; ++ks)
                    acc[m][2 + n] = __builtin_amdgcn_mfma_f32_16x16x32_f16(
                        afl[m][ks], bfb[n][ks], acc[m][2 + n], 0, 0, 0);
        __builtin_amdgcn_s_setprio(0);
        __builtin_amdgcn_s_barrier();
        __builtin_amdgcn_sched_barrier(0);

        // ---- phase 2: read afh; stage B-half1(t+1) ----
        #pragma unroll
        for (int m = 0; m < 4; ++m)
            #pragma unroll
            for (int ks = 0; ks < 2; ++ks)
                afh[m][ks] = ldsfrag(Ab, 64 + m * 16 + fr, ks * 4 + ch);
        if (tk + 1 < NKT) STAGE_HALF(&Bs[nbuf][1][0], Bg1, tk + 1);
        __builtin_amdgcn_s_barrier();
        asm volatile("s_waitcnt lgkmcnt(0)" ::: "memory");
        __builtin_amdgcn_sched_barrier(0);
        __builtin_amdgcn_s_setprio(1);
        #pragma unroll
        for (int m = 0; m < 4; ++m)
            #pragma unroll
            for (int n = 0; n < 2; ++n)
                #pragma unroll
                for (int ks = 0; ks < 2; ++ks)
                    acc[4 + m][n] = __builtin_amdgcn_mfma_f32_16x16x32_f16(
                        afh[m][ks], bfa[n][ks], acc[4 + m][n], 0, 0, 0);
        __builtin_amdgcn_s_setprio(0);
        __builtin_amdgcn_s_barrier();
        __builtin_amdgcn_sched_barrier(0);

        // ---- phase 3: stage A-half0(t+2) into As[buf][0] (dead since p2) ----
        if (tk + 2 < NKT) STAGE_HALF(&As[buf][0][0], Ag0, tk + 2);
        __builtin_amdgcn_s_barrier();
        asm volatile("s_waitcnt lgkmcnt(0)" ::: "memory");
        __builtin_amdgcn_sched_barrier(0);
        __builtin_amdgcn_s_setprio(1);
        #pragma unroll
        for (int m = 0; m < 4; ++m)
            #pragma unroll
            for (int n = 0; n < 2; ++n)
                #pragma unroll
                for (int ks = 0; ks < 2; ++ks)
                    acc[4 + m][2 + n] = __builtin_amdgcn_mfma_f32_16x16x32_f16(
                        afh[m][ks], bfb[n][ks], acc[4 + m][2 + n], 0, 0, 0);
        __builtin_amdgcn_s_setprio(0);
        // boundary: tile t+1 ready when only A0(t+2)'s 2 loads remain in flight
        if (tk + 1 < NKT) {
            if (tk + 2 < NKT) asm volatile("s_waitcnt vmcnt(2)" ::: "memory");
            else              asm volatile("s_waitcnt vmcnt(0)" ::: "memory");
            __builtin_amdgcn_s_barrier();
            __builtin_amdgcn_sched_barrier(0);
        }
    }
    #undef STAGE_HALF

    // epilogue: C row = m0+wm*128+mf*16+(lane>>4)*4+r ; col = n0+wn*64+nf*16+(lane&15)
    const int colf = lane & 15;
    const int rowf = (lane >> 4) * 4;
    #pragma unroll
    for (int mf = 0; mf < 8; ++mf) {
        #pragma unroll
        for (int nf = 0; nf < 4; ++nf) {
            const int n = n0 + wn * 64 + nf * 16 + colf;
            #pragma unroll
            for (int r = 0; r < 4; ++r) {
                const int row = m0 + wm * 128 + mf * 16 + rowf + r;
                float vv = acc[mf][nf][r];
                float sq = vv * vv;
                float other = __shfl_xor(sq, 1, 64);
                if (!(lane & 1)) {
                    float p = fminf((sq + other) * invs[row], 1.0f);
                    out[(size_t)row * DIM + (n >> 1)] = p;
                }
            }
        }
    }
}

extern "C" void kernel_launch(void* const* d_in, const int* in_sizes, int n_in,
                              void* d_out, int out_size, void* d_ws, size_t ws_size,
                              hipStream_t stream) {
    const float* x = (const float*)d_in[0];     // (8192,1,32,32) fp32
    const float* w = (const float*)d_in[1];     // (16,10,3) fp32
    float* out = (float*)d_out;                 // (8192,1,32,32) fp32

    char* ws = (char*)d_ws;
    float*     gates = (float*)(ws + WS_GATES);
    int*       iperm = (int*)(ws + WS_IPERM);
    float*     invs  = (float*)(ws + WS_INVS);
    _Float16*  Xh    = (_Float16*)(ws + WS_XH);
    _Float16*  Bil   = (_Float16*)(ws + WS_BIL);
    // Ucol scratch lives in d_out (4 MB of its 32 MB); consumed by transpose
    // before gemm overwrites every element of d_out.
    _Float16*  Ucol  = (_Float16*)d_out;

    prep_kernel<<<1, 1024, 0, stream>>>(w, gates, iperm);
    normcast_kernel<<<8192, 64, 0, stream>>>(x, Xh, invs);
    ubuild_kernel<<<512, 256, 0, stream>>>(gates, iperm, Ucol);
    transpose_kernel<<<dim3(32, 16), 256, 0, stream>>>(Ucol, Bil);
    gemm_kernel<<<256, 512, 0, stream>>>(Xh, Bil, invs, out);
}